// Round 8
// baseline (635.708 us; speedup 1.0000x reference)
//
#include <hip/hip_runtime.h>
#include <math.h>

// Problem constants
#define BB   2
#define TT   2048
#define CC   1024
#define HH   16
#define DD   64
#define HID  256
#define FFD  4096
#define NTOK (BB*TT)        // 4096
#define CT   64
#define NC   32
#define NBH  32
#define NCHK 1024
#define MB   (1048576ULL)

typedef unsigned short u16;
typedef unsigned int   u32;
typedef __attribute__((ext_vector_type(8))) short frag8;   // 8 bf16 = 4 VGPRs
typedef __attribute__((ext_vector_type(4))) float f32x4;

__device__ __forceinline__ float bf2f(u16 h){
    union { u32 u; float f; } c; c.u = ((u32)h) << 16; return c.f;
}
__device__ __forceinline__ u16 f2bf(float f){
    union { float f; u32 u; } c; c.f = f;
    u32 u = c.u;
    u += 0x7FFFu + ((u >> 16) & 1u);   // RNE
    return (u16)(u >> 16);
}
__device__ __forceinline__ bool is_f32(const u32* flags, int idx) {
    if (idx == -2) return true;
    if (idx < 0)  return false;
    return flags[idx] != 0;
}

// ---------------------------------------------------------------------------
// dtype sniffer (unchanged, verified R3/R5/R6)
// ---------------------------------------------------------------------------
struct InPtrs { const void* p[11]; int n[11]; };

__global__ __launch_bounds__(64)
void sniff_kernel(InPtrs ip, u32* __restrict__ flags)
{
    int lane = threadIdx.x;
    u32 f0 = 0;
    for (int i = 0; i < 11; i++) {
        const u16* p = (const u16*)ip.p[i];
        int cap = ip.n[i] < 256 ? ip.n[i] : 256;
        bool ok = true;
        for (int j = lane; j < cap; j += 64) {
            u16 u = p[j];
            u32 e = (u >> 7) & 0xFFu;
            bool good = (u == 0u) || (u == 0x8000u) || (e >= 64u && e < 192u);
            ok = ok && good;
        }
        unsigned long long ball = __ballot(ok);
        u32 fl = (ball == ~0ull) ? 0u : 1u;
        if (ip.n[i] < 64) fl = f0;
        if (i == 0) f0 = fl;
        if (lane == 0) flags[i] = fl;
    }
}

// XCD-aware block remap (verified R6)
__device__ __forceinline__ void xcd_map(int i, int NB, int gx, int& bm, int& bn)
{
    int per = NB >> 3;
    int iq  = (i & 7) * per + (i >> 3);
    bm = iq / gx;
    bn = iq % gx;
}

// ---------------------------------------------------------------------------
// prefetch helpers: raw-byte load into VGPRs; dtype-convert at LDS-store time
// buf: 8 uint4 (covers 32 f32); bf16 path uses first 4.
// ---------------------------------------------------------------------------
__device__ __forceinline__ void pf_load(const void* p, size_t off, bool f32,
                                        uint4* buf)
{
    if (f32) {
        const float* s = (const float*)p + off;
        #pragma unroll
        for (int j = 0; j < 8; j++) buf[j] = *(const uint4*)(s + j*4);
    } else {
        const u16* s = (const u16*)p + off;
        #pragma unroll
        for (int j = 0; j < 4; j++) buf[j] = *(const uint4*)(s + j*8);
    }
}
__device__ __forceinline__ void pf_store(u16* sdst, bool f32, const uint4* buf)
{
    if (f32) {
        #pragma unroll
        for (int j = 0; j < 8; j++) {
            uint4 w = buf[j];
            const float* f = (const float*)&w;
            u16 tmp[4] = {f2bf(f[0]), f2bf(f[1]), f2bf(f[2]), f2bf(f[3])};
            *(uint2*)(sdst + j*4) = *(const uint2*)tmp;
        }
    } else {
        #pragma unroll
        for (int j = 0; j < 4; j++) *(uint4*)(sdst + j*8) = buf[j];
    }
}

// ---------------------------------------------------------------------------
// NT GEMM, MFMA core, BK=64 + register prefetch. Runtime dtypes (R6 flow).
// C[M,N] = epilogue( A[M,K+] @ B[N,K+]^T ). MODE: 0 plain, 2 relu^2,
// 3 +res(bf16). Split-K via blockIdx.y: koff=z*K, f32 partial at z*M*N when
// of32. 128x128 tile, 256 thr = 4 waves, wave = 4x4 of 16x16x32 MFMA. LDK=72.
// Requires K % 64 == 0.
// ---------------------------------------------------------------------------
template<int MODE>
__global__ __launch_bounds__(256)
void gemm_nt(const void* __restrict__ Av, const void* __restrict__ Bv,
             void* __restrict__ Cm, const void* __restrict__ aux,
             int M, int N, int K, int lda, int ldb,
             const u32* __restrict__ flags, int ai, int bi, int oi)
{
    const bool af32 = is_f32(flags, ai);
    const bool bf32 = is_f32(flags, bi);
    const bool of32 = is_f32(flags, oi);

    constexpr int LDK = 72;
    __shared__ u16 As[128 * LDK];
    __shared__ u16 Bs[128 * LDK];
    const int tid = threadIdx.x;
    int bm, bn;
    xcd_map(blockIdx.x, gridDim.x, N >> 7, bm, bn);
    const int z = blockIdx.y;
    const size_t koff = (size_t)z * K;

    const int row  = tid >> 1;          // 0..127
    const int half = tid & 1;           // which 32-elem k-half of the 64-tile
    const size_t aoff = (size_t)(bm*128 + row)*lda + koff + half*32;
    const size_t boff = (size_t)(bn*128 + row)*ldb + koff + half*32;
    u16* sA = &As[row*LDK + half*32];
    u16* sB = &Bs[row*LDK + half*32];

    const int wave = tid >> 6, lane = tid & 63;
    const int lm = lane & 15, quad = lane >> 4;
    const int wm = (wave >> 1) * 64, wn = (wave & 1) * 64;

    f32x4 acc[4][4];
    #pragma unroll
    for (int i = 0; i < 4; i++)
        #pragma unroll
        for (int j = 0; j < 4; j++)
            acc[i][j] = (f32x4){0.f, 0.f, 0.f, 0.f};

    uint4 pa[8], pb[8];
    pf_load(Av, aoff, af32, pa);
    pf_load(Bv, boff, bf32, pb);

    for (int k0 = 0; k0 < K; k0 += 64) {
        __syncthreads();
        pf_store(sA, af32, pa);
        pf_store(sB, bf32, pb);
        __syncthreads();
        if (k0 + 64 < K) {
            pf_load(Av, aoff + k0 + 64, af32, pa);
            pf_load(Bv, boff + k0 + 64, bf32, pb);
        }
        #pragma unroll
        for (int kk = 0; kk < 2; kk++) {
            frag8 af[4], bf[4];
            #pragma unroll
            for (int i = 0; i < 4; i++) {
                af[i] = *(frag8*)&As[(wm + i*16 + lm)*LDK + kk*32 + quad*8];
                bf[i] = *(frag8*)&Bs[(wn + i*16 + lm)*LDK + kk*32 + quad*8];
            }
            #pragma unroll
            for (int i = 0; i < 4; i++)
                #pragma unroll
                for (int j = 0; j < 4; j++)
                    acc[i][j] = __builtin_amdgcn_mfma_f32_16x16x32_bf16(
                        af[i], bf[j], acc[i][j], 0, 0, 0);
        }
    }

    const size_t coff = (size_t)z * M * N;
    // C/D map (m89/m91): col = lane&15, row = quad*4 + reg
    #pragma unroll
    for (int i = 0; i < 4; i++) {
        #pragma unroll
        for (int j = 0; j < 4; j++) {
            const int gcol = bn*128 + wn + j*16 + lm;
            #pragma unroll
            for (int r = 0; r < 4; r++) {
                const int grow = bm*128 + wm + i*16 + quad*4 + r;
                size_t off = (size_t)grow * N + gcol;
                float vv = acc[i][j][r];
                if constexpr (MODE == 2) { vv = fmaxf(vv, 0.f); vv = vv * vv; }
                if constexpr (MODE == 3) { vv += bf2f(((const u16*)aux)[off]); }
                if (of32) ((float*)Cm)[coff + off] = vv;
                else      ((u16*)Cm)[off]          = f2bf(vv);
            }
        }
    }
}

// ---------------------------------------------------------------------------
// Fused QKV + meta1 GEMM (runtime dtypes, BK=64 + prefetch). bn 0..7 q,
// 8..15 k, 16..23 v, 24..25 hid = relu(x@Wm1^T + bm1) f32. 832 blocks.
// ---------------------------------------------------------------------------
__global__ __launch_bounds__(256)
void gemm_qkvm(const void* __restrict__ Xv,
               const void* __restrict__ Wq, const void* __restrict__ Wk,
               const void* __restrict__ Wv, const void* __restrict__ Wm1,
               const void* __restrict__ bm1,
               u16* __restrict__ q, u16* __restrict__ k, u16* __restrict__ v,
               float* __restrict__ hid, const u32* __restrict__ flags)
{
    constexpr int LDK = 72;
    __shared__ u16 As[128 * LDK];
    __shared__ u16 Bs[128 * LDK];
    const int tid = threadIdx.x;
    int bm, bn;
    xcd_map(blockIdx.x, 832, 26, bm, bn);

    const int bsel = bn >> 3;                    // 0 q, 1 k, 2 v, 3 meta
    const void* Bv = (bsel == 0) ? Wq : (bsel == 1) ? Wk : (bsel == 2) ? Wv : Wm1;
    const bool af32 = is_f32(flags, 0);
    const bool bf32 = is_f32(flags, 1 + bsel);

    const int row  = tid >> 1;
    const int half = tid & 1;
    const size_t aoff = (size_t)(bm*128 + row)*CC + half*32;
    const size_t boff = (size_t)((bn & 7)*128 + row)*CC + half*32;
    u16* sA = &As[row*LDK + half*32];
    u16* sB = &Bs[row*LDK + half*32];

    const int wave = tid >> 6, lane = tid & 63;
    const int lm = lane & 15, quad = lane >> 4;
    const int wm = (wave >> 1) * 64, wn = (wave & 1) * 64;

    f32x4 acc[4][4];
    #pragma unroll
    for (int i = 0; i < 4; i++)
        #pragma unroll
        for (int j = 0; j < 4; j++)
            acc[i][j] = (f32x4){0.f, 0.f, 0.f, 0.f};

    uint4 pa[8], pb[8];
    pf_load(Xv, aoff, af32, pa);
    pf_load(Bv, boff, bf32, pb);

    for (int k0 = 0; k0 < CC; k0 += 64) {
        __syncthreads();
        pf_store(sA, af32, pa);
        pf_store(sB, bf32, pb);
        __syncthreads();
        if (k0 + 64 < CC) {
            pf_load(Xv, aoff + k0 + 64, af32, pa);
            pf_load(Bv, boff + k0 + 64, bf32, pb);
        }
        #pragma unroll
        for (int kk = 0; kk < 2; kk++) {
            frag8 af[4], bf[4];
            #pragma unroll
            for (int i = 0; i < 4; i++) {
                af[i] = *(frag8*)&As[(wm + i*16 + lm)*LDK + kk*32 + quad*8];
                bf[i] = *(frag8*)&Bs[(wn + i*16 + lm)*LDK + kk*32 + quad*8];
            }
            #pragma unroll
            for (int i = 0; i < 4; i++)
                #pragma unroll
                for (int j = 0; j < 4; j++)
                    acc[i][j] = __builtin_amdgcn_mfma_f32_16x16x32_bf16(
                        af[i], bf[j], acc[i][j], 0, 0, 0);
        }
    }

    if (bsel < 3) {
        u16* outp = (bsel == 0) ? q : (bsel == 1) ? k : v;
        #pragma unroll
        for (int i = 0; i < 4; i++) {
            #pragma unroll
            for (int j = 0; j < 4; j++) {
                const int gcol = (bn & 7)*128 + wn + j*16 + lm;
                #pragma unroll
                for (int r = 0; r < 4; r++) {
                    const int grow = bm*128 + wm + i*16 + quad*4 + r;
                    outp[(size_t)grow * CC + gcol] = f2bf(acc[i][j][r]);
                }
            }
        }
    } else {
        const bool biasf = is_f32(flags, 5);
        #pragma unroll
        for (int i = 0; i < 4; i++) {
            #pragma unroll
            for (int j = 0; j < 4; j++) {
                const int gcol = (bn & 7)*128 + wn + j*16 + lm;   // 0..255
                float bia = biasf ? ((const float*)bm1)[gcol]
                                  : bf2f(((const u16*)bm1)[gcol]);
                #pragma unroll
                for (int r = 0; r < 4; r++) {
                    const int grow = bm*128 + wm + i*16 + quad*4 + r;
                    hid[(size_t)grow * HID + gcol] = fmaxf(acc[i][j][r] + bia, 0.f);
                }
            }
        }
    }
}

// ---------------------------------------------------------------------------
// meta2 (unchanged, runtime dtype for Wm2/bm2)
// ---------------------------------------------------------------------------
__global__ __launch_bounds__(256)
void meta2_kernel(const float* __restrict__ hid, const void* __restrict__ Wm2,
                  const void* __restrict__ bm2, float* __restrict__ g,
                  float* __restrict__ dec, const u32* __restrict__ flags)
{
    const bool wf = is_f32(flags, 6);
    const bool bf = is_f32(flags, 7);
    __shared__ float hs[16][257];
    __shared__ float wsm[16][257];
    int tid  = threadIdx.x;
    int tok0 = blockIdx.x * 16;
    for (int i = tid; i < 16*256; i += 256) {
        wsm[i >> 8][i & 255] = wf ? ((const float*)Wm2)[i] : bf2f(((const u16*)Wm2)[i]);
        hs [i >> 8][i & 255] = hid[(size_t)tok0*256 + i];
    }
    __syncthreads();
    int tok = tid >> 4, hh = tid & 15;
    float s = 0.f;
    #pragma unroll 8
    for (int kk = 0; kk < 256; kk++) s = fmaf(hs[tok][kk], wsm[hh][kk], s);
    s += bf ? ((const float*)bm2)[hh] : bf2f(((const u16*)bm2)[hh]);
    float sg = 1.f / (1.f + expf(-s));
    int idx = (tok0 + tok) * HH + hh;
    g[idx]   = sg;
    dec[idx] = 1.f - sg;
}

// ---------------------------------------------------------------------------
// scan pass 1 (unchanged)
// ---------------------------------------------------------------------------
__global__ __launch_bounds__(256)
void scan_pass1(const u16* __restrict__ kbuf, const u16* __restrict__ vbuf,
                const float* __restrict__ g, const float* __restrict__ dec,
                float* __restrict__ Mb, float* __restrict__ Pb)
{
    __shared__ float ks[64*64];
    __shared__ float vs[64*64];
    __shared__ float dd[64], gg[64], cum[64], sw[64];
    int tid = threadIdx.x;
    int bhc = blockIdx.x;
    int c = bhc & 31, h = (bhc >> 5) & 15, b = bhc >> 9;
    int t0 = c * CT;
    size_t rowbase = ((size_t)(b*TT + t0))*CC + h*DD;

    for (int i = tid; i < 4096; i += 256) {
        int s = i >> 6, d = i & 63;
        ks[i] = bf2f(kbuf[rowbase + (size_t)s*CC + d]);
        vs[i] = bf2f(vbuf[rowbase + (size_t)s*CC + d]);
    }
    if (tid < 64) {
        int gidx = (b*TT + t0 + tid)*HH + h;
        dd[tid] = dec[gidx];
        gg[tid] = g[gidx];
    }
    __syncthreads();
    if (tid == 0) {
        float cs = 0.f;
        for (int s = 0; s < 64; s++) { cs += logf(fmaxf(dd[s], 1e-30f)); cum[s] = cs; }
    }
    __syncthreads();
    float ctot = cum[63];
    if (tid < 64) sw[tid] = gg[tid] * expf(ctot - cum[tid]);
    __syncthreads();

    int d0 = (tid >> 4) * 4, e0 = (tid & 15) * 4;
    float m[4][4] = {};
    for (int s = 0; s < 64; s++) {
        float w = sw[s];
        float4 kv = *(const float4*)&ks[s*64 + d0];
        float4 vv = *(const float4*)&vs[s*64 + e0];
        float a0 = w*kv.x, a1 = w*kv.y, a2 = w*kv.z, a3 = w*kv.w;
        m[0][0]=fmaf(a0,vv.x,m[0][0]); m[0][1]=fmaf(a0,vv.y,m[0][1]); m[0][2]=fmaf(a0,vv.z,m[0][2]); m[0][3]=fmaf(a0,vv.w,m[0][3]);
        m[1][0]=fmaf(a1,vv.x,m[1][0]); m[1][1]=fmaf(a1,vv.y,m[1][1]); m[1][2]=fmaf(a1,vv.z,m[1][2]); m[1][3]=fmaf(a1,vv.w,m[1][3]);
        m[2][0]=fmaf(a2,vv.x,m[2][0]); m[2][1]=fmaf(a2,vv.y,m[2][1]); m[2][2]=fmaf(a2,vv.z,m[2][2]); m[2][3]=fmaf(a2,vv.w,m[2][3]);
        m[3][0]=fmaf(a3,vv.x,m[3][0]); m[3][1]=fmaf(a3,vv.y,m[3][1]); m[3][2]=fmaf(a3,vv.z,m[3][2]); m[3][3]=fmaf(a3,vv.w,m[3][3]);
    }
    size_t base = (size_t)bhc * 4096;
    #pragma unroll
    for (int i = 0; i < 4; i++) {
        float4 o = make_float4(m[i][0], m[i][1], m[i][2], m[i][3]);
        *(float4*)&Mb[base + (size_t)(d0 + i)*64 + e0] = o;
    }
    if (tid == 0) Pb[bhc] = expf(ctot);
}

// ---------------------------------------------------------------------------
// scan pass 2 (unchanged)
// ---------------------------------------------------------------------------
__global__ __launch_bounds__(256)
void scan_pass2(float* __restrict__ MS, const float* __restrict__ Pb)
{
    int bh = blockIdx.x, tid = threadIdx.x;
    float st[16];
    #pragma unroll
    for (int i = 0; i < 16; i++) st[i] = 0.f;
    for (int c = 0; c < NC; c++) {
        size_t base = ((size_t)bh*NC + c) * 4096;
        float p = Pb[bh*NC + c];
        #pragma unroll
        for (int i = 0; i < 16; i++) {
            size_t e = base + tid + i*256;
            float m = MS[e];
            MS[e] = st[i];
            st[i] = fmaf(p, st[i], m);
        }
    }
}

// ---------------------------------------------------------------------------
// fused scan pass 3 (unchanged)
// ---------------------------------------------------------------------------
__global__ __launch_bounds__(256)
void scan_pass3(const u16* __restrict__ qbuf, const u16* __restrict__ kbuf,
                const u16* __restrict__ vbuf, const float* __restrict__ g,
                const float* __restrict__ dec, const float* __restrict__ Sb,
                u16* __restrict__ y)
{
    __shared__ float qs[64*64];
    __shared__ float kt[64*68];
    __shared__ float vs[64*64];
    __shared__ u16   Aws[4096];
    __shared__ float dd[64], gg[64], cum[64];
    int tid = threadIdx.x;
    int bhc = blockIdx.x;
    int c = bhc & 31, h = (bhc >> 5) & 15, b = bhc >> 9;
    int t0 = c * CT;
    size_t rowbase = ((size_t)(b*TT + t0))*CC + h*DD;

    for (int i = tid; i < 4096; i += 256) {
        int s = i >> 6, d = i & 63;
        size_t gi = rowbase + (size_t)s*CC + d;
        qs[i]        = bf2f(qbuf[gi]);
        kt[d*68 + s] = bf2f(kbuf[gi]);
        vs[i]        = bf2f(vbuf[gi]);
    }
    if (tid < 64) {
        int gidx = (b*TT + t0 + tid)*HH + h;
        dd[tid] = dec[gidx];
        gg[tid] = g[gidx];
    }
    __syncthreads();
    if (tid == 0) {
        float cs = 0.f;
        for (int s = 0; s < 64; s++) { cs += logf(fmaxf(dd[s], 1e-30f)); cum[s] = cs; }
    }
    __syncthreads();

    const int tt0 = (tid >> 4) * 4, ss0 = (tid & 15) * 4;
    float a1[4][4] = {};
    for (int d = 0; d < 64; d++) {
        float4 kv = *(const float4*)&kt[d*68 + ss0];
        #pragma unroll
        for (int i = 0; i < 4; i++) {
            float qv = qs[(tt0 + i)*64 + d];
            a1[i][0] = fmaf(qv, kv.x, a1[i][0]);
            a1[i][1] = fmaf(qv, kv.y, a1[i][1]);
            a1[i][2] = fmaf(qv, kv.z, a1[i][2]);
            a1[i][3] = fmaf(qv, kv.w, a1[i][3]);
        }
    }
    #pragma unroll
    for (int i = 0; i < 4; i++) {
        int t = tt0 + i;
        float ct = cum[t];
        #pragma unroll
        for (int j = 0; j < 4; j++) {
            int s = ss0 + j;
            float w = (s <= t) ? gg[s] * expf(ct - cum[s]) : 0.f;
            Aws[t*64 + s] = f2bf(w * a1[i][j]);
        }
    }
    __syncthreads();
    float* Ss = kt;
    size_t sbase = (size_t)bhc * 4096;
    for (int i = tid; i < 4096; i += 256) Ss[i] = Sb[sbase + i];
    __syncthreads();

    const int e0 = ss0;
    float o1[4][4] = {}, o2[4][4] = {};
    for (int s = 0; s < 64; s++) {
        float4 vv = *(const float4*)&vs[s*64 + e0];
        #pragma unroll
        for (int i = 0; i < 4; i++) {
            float av = bf2f(Aws[(tt0 + i)*64 + s]);
            o1[i][0] = fmaf(av, vv.x, o1[i][0]);
            o1[i][1] = fmaf(av, vv.y, o1[i][1]);
            o1[i][2] = fmaf(av, vv.z, o1[i][2]);
            o1[i][3] = fmaf(av, vv.w, o1[i][3]);
        }
    }
    for (int d = 0; d < 64; d++) {
        float4 sv = *(const float4*)&Ss[d*64 + e0];
        #pragma unroll
        for (int i = 0; i < 4; i++) {
            float qv = qs[(tt0 + i)*64 + d];
            o2[i][0] = fmaf(qv, sv.x, o2[i][0]);
            o2[i][1] = fmaf(qv, sv.y, o2[i][1]);
            o2[i][2] = fmaf(qv, sv.z, o2[i][2]);
            o2[i][3] = fmaf(qv, sv.w, o2[i][3]);
        }
    }
    #pragma unroll
    for (int i = 0; i < 4; i++) {
        float cd = expf(cum[tt0 + i]);
        size_t obase = rowbase + (size_t)(tt0 + i)*CC + e0;
        #pragma unroll
        for (int j = 0; j < 4; j++)
            y[obase + j] = f2bf(fmaf(cd, o2[i][j], o1[i][j]));
    }
}

// ---------------------------------------------------------------------------
// rmsnorm v2 (unchanged): combine split-K partials, emit residual + normed
// ---------------------------------------------------------------------------
__global__ __launch_bounds__(256)
void rmsnorm_kernel(const float* __restrict__ p0, const float* __restrict__ p1,
                    u16* __restrict__ yres, u16* __restrict__ yn)
{
    __shared__ float red[4];
    __shared__ float sscale;
    int row = blockIdx.x, tid = threadIdx.x;
    size_t base = (size_t)row*CC + tid*4;
    float4 a = *(const float4*)&p0[base];
    float4 b = *(const float4*)&p1[base];
    float v0 = a.x + b.x, v1 = a.y + b.y, v2 = a.z + b.z, v3 = a.w + b.w;
    yres[base + 0] = f2bf(v0);
    yres[base + 1] = f2bf(v1);
    yres[base + 2] = f2bf(v2);
    yres[base + 3] = f2bf(v3);
    float p = v0*v0 + v1*v1 + v2*v2 + v3*v3;
    #pragma unroll
    for (int off = 32; off > 0; off >>= 1) p += __shfl_down(p, off, 64);
    if ((tid & 63) == 0) red[tid >> 6] = p;
    __syncthreads();
    if (tid == 0) {
        float tot = red[0] + red[1] + red[2] + red[3];
        sscale = rsqrtf(tot * (1.0f/1024.0f) + 1.1920928955078125e-07f);
    }
    __syncthreads();
    float sc = sscale;
    yn[base + 0] = f2bf(v0 * sc);
    yn[base + 1] = f2bf(v1 * sc);
    yn[base + 2] = f2bf(v2 * sc);
    yn[base + 3] = f2bf(v3 * sc);
}

// ---------------------------------------------------------------------------
// Workspace: EXACT R6 layout (passed):
// Phase A: q 0..8 | k 8..16 | v 16..24 | hid 24..28 | g/dec/Pb 28..28.5 |
//          MS 29..45.  Phase B: yat=q alias | p0 8..24, p1 24..40 |
//          yres 0..8 | yn 40..48 | h1 8..40.  flags @ 48 MB.
// ---------------------------------------------------------------------------
extern "C" void kernel_launch(void* const* d_in, const int* in_sizes, int n_in,
                              void* d_out, int out_size, void* d_ws, size_t ws_size,
                              hipStream_t stream)
{
    char* ws = (char*)d_ws;
    u16*   q    = (u16*)  (ws + 0*MB);
    u16*   k    = (u16*)  (ws + 8*MB);
    u16*   v    = (u16*)  (ws + 16*MB);
    float* hid  = (float*)(ws + 24*MB);
    float* g    = (float*)(ws + 28*MB);
    float* dec  = (float*)(ws + 28*MB + 262144);
    float* Pb   = (float*)(ws + 28*MB + 524288);
    float* MS   = (float*)(ws + 29*MB);
    u16*   yat  = q;                      // pass3 writes over q (exact alias)
    float* p0   = (float*)(ws + 8*MB);    // proj split-K partials (f32)
    u16*   yres = (u16*)  (ws + 0*MB);    // over yat after proj
    u16*   yn   = (u16*)  (ws + 40*MB);
    u16*   h1   = (u16*)  (ws + 8*MB);    // over p0/p1 after rmsnorm
    u32*   flags= (u32*)  (ws + 48*MB);

    InPtrs ip;
    for (int i = 0; i < 11; i++) { ip.p[i] = d_in[i]; ip.n[i] = in_sizes[i]; }
    sniff_kernel<<<1, 64, 0, stream>>>(ip, flags);

    // fused qkv + meta1 (832 blocks, XCD-swizzled)
    gemm_qkvm<<<832, 256, 0, stream>>>(d_in[0], d_in[1], d_in[2], d_in[3],
                                       d_in[4], d_in[5], q, k, v, hid, flags);
    meta2_kernel<<<NTOK/16, 256, 0, stream>>>(hid, d_in[6], d_in[7], g, dec, flags);
    // chunked gated linear-attention scan
    scan_pass1<<<NCHK, 256, 0, stream>>>(k, v, g, dec, MS, Pb);
    scan_pass2<<<NBH, 256, 0, stream>>>(MS, Pb);
    scan_pass3<<<NCHK, 256, 0, stream>>>(q, k, v, g, dec, MS, yat);
    // proj: split-K x2 -> f32 partials p0,p1 (512 concurrent blocks)
    gemm_nt<0><<<dim3(256, 2), 256, 0, stream>>>(yat, d_in[8], p0, nullptr,
        NTOK, CC, 512, CC, CC, flags, -1, 8, -2);
    // rmsnorm: combine partials, emit residual (bf16) + normed (bf16)
    rmsnorm_kernel<<<NTOK, 256, 0, stream>>>(p0, p0 + (size_t)NTOK*CC, yres, yn);
    // squared-relu MLP
    gemm_nt<2><<<dim3(1024, 1), 256, 0, stream>>>(yn, d_in[9], h1, nullptr,
        NTOK, FFD, CC, CC, CC, flags, -1, 9, -1);
    gemm_nt<3><<<dim3(256, 1), 256, 0, stream>>>(h1, d_in[10], d_out, yres,
        NTOK, CC, FFD, FFD, FFD, flags, -1, 10, 0);
}